// Round 1
// baseline (80.017 us; speedup 1.0000x reference)
//
#include <hip/hip_runtime.h>
#include <hip/hip_bf16.h>

// JointLengthLoss: mean over [B,20] of |  ||pred_a - pred_b|| - ||gt_a - gt_b|| | / ||gt_a - gt_b||
// B = 524288, joints [B,21,3] f32. Memory-bound streaming reduction.

#define SAMPLES_PER_BLOCK 256
#define FLOATS_PER_SAMPLE 63           // 21 joints * 3
#define TILE_FLOATS (SAMPLES_PER_BLOCK * FLOATS_PER_SAMPLE)  // 16128

__device__ __constant__ const int BONE_A[20] = {3,2,20,8,9,10,20,4,5,6,20,1,0,16,17,18,0,12,13,14};
__device__ __constant__ const int BONE_B[20] = {2,20,8,9,10,11,4,5,6,7,1,0,16,17,18,19,12,13,14,15};

__global__ __launch_bounds__(256, 2)
void jll_partial_kernel(const float* __restrict__ pred,
                        const float* __restrict__ gt,
                        float* __restrict__ partials) {
    __shared__ float lds[TILE_FLOATS];          // 63 KiB
    const int tid = threadIdx.x;
    const size_t tile_base = (size_t)blockIdx.x * TILE_FLOATS;

    // ---- stage pred tile (coalesced float4) ----
    {
        const float4* src = reinterpret_cast<const float4*>(pred + tile_base);
        float4* dst = reinterpret_cast<float4*>(lds);
        #pragma unroll
        for (int idx = tid; idx < TILE_FLOATS / 4; idx += 256) dst[idx] = src[idx];
    }
    __syncthreads();

    // ---- pred bone lengths from LDS (stride-63 = odd -> conflict-free) ----
    float pl[20];
    {
        const float* my = lds + tid * FLOATS_PER_SAMPLE;
        float jx[21], jy[21], jz[21];
        #pragma unroll
        for (int j = 0; j < 21; ++j) {
            jx[j] = my[j * 3 + 0];
            jy[j] = my[j * 3 + 1];
            jz[j] = my[j * 3 + 2];
        }
        #pragma unroll
        for (int b = 0; b < 20; ++b) {
            const int a = BONE_A[b], c = BONE_B[b];
            float dx = jx[a] - jx[c];
            float dy = jy[a] - jy[c];
            float dz = jz[a] - jz[c];
            pl[b] = sqrtf(dx * dx + dy * dy + dz * dz);
        }
    }
    __syncthreads();

    // ---- stage gt tile ----
    {
        const float4* src = reinterpret_cast<const float4*>(gt + tile_base);
        float4* dst = reinterpret_cast<float4*>(lds);
        #pragma unroll
        for (int idx = tid; idx < TILE_FLOATS / 4; idx += 256) dst[idx] = src[idx];
    }
    __syncthreads();

    // ---- gt lengths + relative error ----
    float sum = 0.0f;
    {
        const float* my = lds + tid * FLOATS_PER_SAMPLE;
        float jx[21], jy[21], jz[21];
        #pragma unroll
        for (int j = 0; j < 21; ++j) {
            jx[j] = my[j * 3 + 0];
            jy[j] = my[j * 3 + 1];
            jz[j] = my[j * 3 + 2];
        }
        #pragma unroll
        for (int b = 0; b < 20; ++b) {
            const int a = BONE_A[b], c = BONE_B[b];
            float dx = jx[a] - jx[c];
            float dy = jy[a] - jy[c];
            float dz = jz[a] - jz[c];
            float gl = sqrtf(dx * dx + dy * dy + dz * dz);
            sum += fabsf(pl[b] - gl) / gl;
        }
    }

    // ---- block reduction: wave64 shuffle, then cross-wave via LDS ----
    #pragma unroll
    for (int off = 32; off > 0; off >>= 1)
        sum += __shfl_down(sum, off);

    __shared__ float wsum[4];
    const int lane = tid & 63;
    const int wid  = tid >> 6;
    if (lane == 0) wsum[wid] = sum;
    __syncthreads();
    if (tid == 0)
        partials[blockIdx.x] = wsum[0] + wsum[1] + wsum[2] + wsum[3];
}

__global__ __launch_bounds__(256)
void jll_final_kernel(const float* __restrict__ partials, int nparts,
                      float* __restrict__ out, float inv_count) {
    const int tid = threadIdx.x;
    float sum = 0.0f;
    for (int i = tid; i < nparts; i += 256) sum += partials[i];

    #pragma unroll
    for (int off = 32; off > 0; off >>= 1)
        sum += __shfl_down(sum, off);

    __shared__ float wsum[4];
    const int lane = tid & 63;
    const int wid  = tid >> 6;
    if (lane == 0) wsum[wid] = sum;
    __syncthreads();
    if (tid == 0)
        out[0] = (wsum[0] + wsum[1] + wsum[2] + wsum[3]) * inv_count;
}

extern "C" void kernel_launch(void* const* d_in, const int* in_sizes, int n_in,
                              void* d_out, int out_size, void* d_ws, size_t ws_size,
                              hipStream_t stream) {
    const float* pred = (const float*)d_in[0];
    const float* gt   = (const float*)d_in[1];
    float* out = (float*)d_out;
    float* partials = (float*)d_ws;

    const int nsamples = in_sizes[0] / FLOATS_PER_SAMPLE;   // 524288
    const int nblocks  = nsamples / SAMPLES_PER_BLOCK;      // 2048 (exact)

    jll_partial_kernel<<<nblocks, 256, 0, stream>>>(pred, gt, partials);

    const float inv_count = 1.0f / ((float)nsamples * 20.0f);
    jll_final_kernel<<<1, 256, 0, stream>>>(partials, nblocks, out, inv_count);
}